// Round 2
// baseline (118.378 us; speedup 1.0000x reference)
//
#include <hip/hip_runtime.h>
#include <math.h>

#ifndef M_PI
#define M_PI 3.14159265358979323846
#endif

constexpr int T_LEN = 4096;
constexpr int KMIN = 41;
constexpr int KMAX = 2047;
constexpr float NK_F = 2007.0f;

__device__ __forceinline__ void sincos_rev(float rev, float& s, float& c) {
    // hardware v_sin/v_cos take REVOLUTIONS; rev is exact (m / 2^n)
    s = __builtin_amdgcn_sinf(rev);
    c = __builtin_amdgcn_cosf(rev);
}

// ---------------------------------------------------------------------------
// Stage A: As[b][b2][r] = sum_a x[b, 64a + b2] * e^{-2pi i r a / 64}
// grid: 32 b x 8 slices = 256 blocks, 512 threads (8 waves/CU across chip).
// Twiddle via complex recurrence (1 sincos/thread, 4 FMA/iter, full-rate).
// ---------------------------------------------------------------------------
__global__ __launch_bounds__(512) void dft_stageA_kernel(const float* __restrict__ x,
                                                         float2* __restrict__ As) {
    const int b = blockIdx.x >> 3;
    const int slice = blockIdx.x & 7;
    const int tid = threadIdx.x;

    __shared__ float xs[T_LEN];
    const float* xr = x + (size_t)b * T_LEN;
    for (int i = tid; i < T_LEN; i += 512) xs[i] = xr[i];
    __syncthreads();

    const int p = slice * 512 + tid;   // output index in [0, 4096)
    const int r = p & 63;              // = lane -> coalesced store
    const int b2 = p >> 6;             // wave-uniform -> xs broadcast reads

    float s, c;
    sincos_rev((float)r * (1.0f / 64.0f), s, c);   // step = e^{-2pi i r/64} = (c, -s)
    float wr = 1.f, wi = 0.f, re = 0.f, im = 0.f;
#pragma unroll
    for (int a = 0; a < 64; ++a) {
        float xv = xs[(a << 6) + b2];
        re = fmaf(xv, wr, re);
        im = fmaf(xv, wi, im);
        float t = fmaf(wr, c, wi * s);       // (wr,wi) *= (c,-s)
        wi = fmaf(wi, c, -(wr * s));
        wr = t;
    }
    As[((size_t)b << 12) + (b2 << 6) + r] = make_float2(re, im);
}

// ---------------------------------------------------------------------------
// Stage B: X[k] = sum_b2 A[b2, r=k&63] * e^{-2pi i k b2 / 4096}, then the
// log-log regression entirely in one pass:
//   cov = S_lklp - n*mlk*mlp,  var = S_lk2 - n*mlk^2   (== reference centering)
// grid: 32 blocks x 1024 threads (4 waves/SIMD). A reads are coalesced (r=lane).
// ---------------------------------------------------------------------------
__global__ __launch_bounds__(1024) void spec_reg_kernel(const float2* __restrict__ As,
                                                        float* __restrict__ alpha_out) {
    const int b = blockIdx.x;
    const int tid = threadIdx.x;
    const float2* Ab = As + ((size_t)b << 12);

    float s_lk = 0.f, s_lp = 0.f, s_lk2 = 0.f, s_lklp = 0.f;

    for (int k = KMIN + tid; k <= KMAX; k += 1024) {
        const int r = k & 63;
        float s, c;
        sincos_rev((float)k * (1.0f / 4096.0f), s, c);  // step = (c, -s)
        float wr = 1.f, wi = 0.f, xre = 0.f, xim = 0.f;
#pragma unroll
        for (int bb = 0; bb < 64; ++bb) {
            float2 A = Ab[(bb << 6) + r];
            xre = fmaf(A.x, wr, fmaf(-A.y, wi, xre));   // Re{A * w}
            xim = fmaf(A.x, wi, fmaf(A.y, wr, xim));    // Im{A * w}
            float t = fmaf(wr, c, wi * s);
            wi = fmaf(wi, c, -(wr * s));
            wr = t;
        }
        float power = xre * xre + xim * xim;
        float lp = logf(power + 1e-10f);
        float lk = logf((float)k * (1.0f / 4096.0f) + 1e-10f);
        s_lk += lk;
        s_lp += lp;
        s_lk2 = fmaf(lk, lk, s_lk2);
        s_lklp = fmaf(lk, lp, s_lklp);
    }

    // block-reduce the 4 sums
    for (int off = 32; off > 0; off >>= 1) {
        s_lk   += __shfl_down(s_lk, off, 64);
        s_lp   += __shfl_down(s_lp, off, 64);
        s_lk2  += __shfl_down(s_lk2, off, 64);
        s_lklp += __shfl_down(s_lklp, off, 64);
    }
    __shared__ float red[16][4];
    const int wid = tid >> 6, lane = tid & 63;
    if (lane == 0) {
        red[wid][0] = s_lk; red[wid][1] = s_lp;
        red[wid][2] = s_lk2; red[wid][3] = s_lklp;
    }
    __syncthreads();
    if (tid == 0) {
        float t0 = 0.f, t1 = 0.f, t2 = 0.f, t3 = 0.f;
        for (int w = 0; w < 16; ++w) {
            t0 += red[w][0]; t1 += red[w][1];
            t2 += red[w][2]; t3 += red[w][3];
        }
        const float mlk = t0 * (1.0f / NK_F);
        const float mlp = t1 * (1.0f / NK_F);
        const float cov = t3 - NK_F * mlk * mlp;
        const float var = t2 - NK_F * mlk * mlk;
        float beta = -cov / (var + 1e-10f);
        float D = (3.0f - beta) * 0.5f;
        D = fminf(fmaxf(D, 0.5f), 1.5f);
        float al = 1.0f + 0.8f * (D - 1.0f);
        al = fminf(fmaxf(al, 0.1f), 3.0f);
        alpha_out[b] = al;
    }
}

// ---------------------------------------------------------------------------
// Fallback (ws too small): single-kernel alpha, known-good from round 1.
// ---------------------------------------------------------------------------
__global__ __launch_bounds__(256) void alpha_kernel(const float* __restrict__ x,
                                                    float* __restrict__ alpha_out) {
    const int b = blockIdx.x;
    const int tid = threadIdx.x;

    __shared__ float xs[T_LEN];
    __shared__ float2 As[64 * 64];
    __shared__ float rbuf[8];

    const float* xr = x + (size_t)b * T_LEN;
    for (int i = tid; i < T_LEN; i += 256) xs[i] = xr[i];
    __syncthreads();

    for (int i = 0; i < 16; ++i) {
        int p = tid + 256 * i;
        int b2 = p >> 6;
        int r  = p & 63;
        float re = 0.f, im = 0.f;
        int m = 0;
        for (int a = 0; a < 64; ++a) {
            float s, c;
            sincos_rev((float)m * (1.0f / 64.0f), s, c);
            float xv = xs[(a << 6) + b2];
            re = fmaf(xv, c, re);
            im = fmaf(xv, -s, im);
            m = (m + r) & 63;
        }
        As[(b2 << 6) + r] = make_float2(re, im);
    }
    __syncthreads();

    float lk_arr[8], lp_arr[8];
    float sum_lk = 0.f, sum_lp = 0.f;
#pragma unroll
    for (int i = 0; i < 8; ++i) {
        int k = KMIN + tid + 256 * i;
        lk_arr[i] = 0.f; lp_arr[i] = 0.f;
        if (k <= KMAX) {
            int r = k & 63;
            float xre = 0.f, xim = 0.f;
            int m = 0;
            for (int bb = 0; bb < 64; ++bb) {
                float s, c;
                sincos_rev((float)m * (1.0f / 4096.0f), s, c);
                float2 A = As[(bb << 6) + r];
                xre = fmaf(A.x, c, fmaf(A.y,  s, xre));
                xim = fmaf(A.y, c, fmaf(-A.x, s, xim));
                m = (m + k) & 4095;
            }
            float power = xre * xre + xim * xim;
            float lp = logf(power + 1e-10f);
            float lk = logf((float)k * (1.0f / 4096.0f) + 1e-10f);
            lk_arr[i] = lk; lp_arr[i] = lp;
            sum_lk += lk; sum_lp += lp;
        }
    }

    float a1 = sum_lk, a2 = sum_lp;
    for (int off = 32; off > 0; off >>= 1) {
        a1 += __shfl_down(a1, off, 64);
        a2 += __shfl_down(a2, off, 64);
    }
    const int wid = tid >> 6, lane = tid & 63;
    if (lane == 0) { rbuf[wid] = a1; rbuf[4 + wid] = a2; }
    __syncthreads();
    const float mean_lk = (rbuf[0] + rbuf[1] + rbuf[2] + rbuf[3]) * (1.0f / NK_F);
    const float mean_lp = (rbuf[4] + rbuf[5] + rbuf[6] + rbuf[7]) * (1.0f / NK_F);
    __syncthreads();

    float cov = 0.f, var = 0.f;
#pragma unroll
    for (int i = 0; i < 8; ++i) {
        int k = KMIN + tid + 256 * i;
        if (k <= KMAX) {
            float lkc = lk_arr[i] - mean_lk;
            float lpc = lp_arr[i] - mean_lp;
            cov = fmaf(lkc, lpc, cov);
            var = fmaf(lkc, lkc, var);
        }
    }
    float c1 = cov, c2 = var;
    for (int off = 32; off > 0; off >>= 1) {
        c1 += __shfl_down(c1, off, 64);
        c2 += __shfl_down(c2, off, 64);
    }
    if (lane == 0) { rbuf[wid] = c1; rbuf[4 + wid] = c2; }
    __syncthreads();
    if (tid == 0) {
        float covT = rbuf[0] + rbuf[1] + rbuf[2] + rbuf[3];
        float varT = rbuf[4] + rbuf[5] + rbuf[6] + rbuf[7];
        float beta = -covT / (varT + 1e-10f);
        float D = (3.0f - beta) * 0.5f;
        D = fminf(fmaxf(D, 0.5f), 1.5f);
        float al = 1.0f + 0.8f * (D - 1.0f);
        al = fminf(fmaxf(al, 0.1f), 3.0f);
        alpha_out[b] = al;
    }
}

// ---------------------------------------------------------------------------
// logits[b, v] = 10*|amp*(cos(ph)*psi0 + sin(ph)*psi1)| / (|amp| + 1e-8)
// (unchanged from passing round-1 kernel; libm sinf keeps the v=0 amp
//  residual matched to the XLA reference)
// ---------------------------------------------------------------------------
__global__ __launch_bounds__(256) void logits_kernel(const float* __restrict__ psi,
                                                     const float* __restrict__ alpha,
                                                     float* __restrict__ out) {
    const int b = blockIdx.y;
    const int j = blockIdx.x * 256 + threadIdx.x;   // [0, 32000) float4 index
    const float al = alpha[b];
    const float p0 = psi[b * 4 + 0];
    const float p1 = psi[b * 4 + 1];

    const float OMEGA = (float)(2.0 * M_PI);
    const float KWAVE = (float)(2.0 * M_PI / 0.5);

    float tmp[4];
#pragma unroll
    for (int u = 0; u < 4; ++u) {
        int v = j * 4 + u;
        float lam = (float)v / 128000.0f;
        float amp = sinf(OMEGA + al * lam);
        float ph  = OMEGA - KWAVE * lam + 0.01f * (lam * lam);
        float s = sinf(ph);
        float c = cosf(ph);
        float coup = (amp * c * p0 + amp * s * p1) / (fabsf(amp) + 1e-8f);
        tmp[u] = 10.0f * fabsf(coup);
    }
    float4 res;
    res.x = tmp[0]; res.y = tmp[1]; res.z = tmp[2]; res.w = tmp[3];
    reinterpret_cast<float4*>(out)[(size_t)b * 32000 + j] = res;
}

extern "C" void kernel_launch(void* const* d_in, const int* in_sizes, int n_in,
                              void* d_out, int out_size, void* d_ws, size_t ws_size,
                              hipStream_t stream) {
    const float* x   = (const float*)d_in[0];   // [32, 4096] f32
    const float* psi = (const float*)d_in[1];   // [32, 4] f32
    float* out = (float*)d_out;                 // [32, 128000] f32

    const size_t as_bytes = (size_t)32 * 4096 * sizeof(float2);   // 1 MiB

    if (ws_size >= as_bytes + 128) {
        float2* As   = (float2*)d_ws;
        float* alpha = (float*)((char*)d_ws + as_bytes);
        dft_stageA_kernel<<<256, 512, 0, stream>>>(x, As);
        spec_reg_kernel<<<32, 1024, 0, stream>>>(As, alpha);
        logits_kernel<<<dim3(125, 32), 256, 0, stream>>>(psi, alpha, out);
    } else {
        float* alpha = (float*)d_ws;            // 32 floats scratch
        alpha_kernel<<<32, 256, 0, stream>>>(x, alpha);
        logits_kernel<<<dim3(125, 32), 256, 0, stream>>>(psi, alpha, out);
    }
}

// Round 3
// 22.437 us; speedup vs baseline: 5.2761x; 5.2761x over previous
//
#include <hip/hip_runtime.h>
#include <math.h>

#ifndef M_PI
#define M_PI 3.14159265358979323846
#endif

constexpr int T_LEN = 4096;
constexpr int KMIN = 41;
constexpr int KMAX = 2047;
constexpr float NK_F = 2007.0f;
constexpr float INV2PI = 0.15915494309189535f;
constexpr float C2 = 0.0015915494f;      // 0.01 / (2*pi)
constexpr float DREV = 2.782754e-8f;     // (float(2pi) - 2pi) / (2pi)
constexpr float AMP0 = 1.7484556e-7f;    // sin(float(2pi)) == reference amp at v=0

__device__ __forceinline__ void sincos_rev(float rev, float& s, float& c) {
    // hardware v_sin/v_cos take REVOLUTIONS
    s = __builtin_amdgcn_sinf(rev);
    c = __builtin_amdgcn_cosf(rev);
}

// ---------------------------------------------------------------------------
// Stage A: As[b][b2][r] = sum_a x[b, 64a + b2] * e^{-2pi i r a / 64}
// grid: 32 b x 8 slices = 256 blocks, 512 threads.
// Twiddle via complex recurrence (1 sincos/thread, full-rate FMAs).
// ---------------------------------------------------------------------------
__global__ __launch_bounds__(512) void dft_stageA_kernel(const float* __restrict__ x,
                                                         float2* __restrict__ As) {
    const int b = blockIdx.x >> 3;
    const int slice = blockIdx.x & 7;
    const int tid = threadIdx.x;

    __shared__ float xs[T_LEN];
    const float* xr = x + (size_t)b * T_LEN;
    for (int i = tid; i < T_LEN; i += 512) xs[i] = xr[i];
    __syncthreads();

    const int p = slice * 512 + tid;   // output index in [0, 4096)
    const int r = p & 63;              // = lane -> coalesced store
    const int b2 = p >> 6;             // wave-uniform -> xs broadcast reads

    float s, c;
    sincos_rev((float)r * (1.0f / 64.0f), s, c);   // step = (c, -s)
    float wr = 1.f, wi = 0.f, re = 0.f, im = 0.f;
#pragma unroll
    for (int a = 0; a < 64; ++a) {
        float xv = xs[(a << 6) + b2];
        re = fmaf(xv, wr, re);
        im = fmaf(xv, wi, im);
        float t = fmaf(wr, c, wi * s);
        wi = fmaf(wi, c, -(wr * s));
        wr = t;
    }
    As[((size_t)b << 12) + (b2 << 6) + r] = make_float2(re, im);
}

// ---------------------------------------------------------------------------
// Stage B (partial): one k per thread, A-slice staged in LDS (SoA planes:
// 2-way bank aliasing only). grid: (8 slices, 32 b) x 256 threads = 256
// blocks -> whole chip. Each block emits float4 partial sums
// (S_lk, S_lP, S_lk2, S_lklP) for its ~251 k-bins.
// ---------------------------------------------------------------------------
__global__ __launch_bounds__(256) void spec_partial_kernel(const float2* __restrict__ As,
                                                           float4* __restrict__ partials) {
    const int slice = blockIdx.x;
    const int b = blockIdx.y;
    const int tid = threadIdx.x;

    __shared__ float Ar[4096];
    __shared__ float Ai[4096];
    __shared__ float4 red[4];

    const float2* Ab = As + ((size_t)b << 12);
    for (int i = tid; i < 4096; i += 256) {
        float2 a = Ab[i];
        Ar[i] = a.x; Ai[i] = a.y;
    }
    __syncthreads();

    const int idx = slice * 256 + tid;
    const int k = KMIN + idx;
    float s_lk = 0.f, s_lp = 0.f, s_lk2 = 0.f, s_lklp = 0.f;

    if (k <= KMAX) {
        const int r = k & 63;
        float s, c;
        sincos_rev((float)k * (1.0f / 4096.0f), s, c);  // step = (c, -s)
        float wr = 1.f, wi = 0.f, xre = 0.f, xim = 0.f;
#pragma unroll
        for (int bb = 0; bb < 64; ++bb) {
            const float ax = Ar[(bb << 6) + r];
            const float ay = Ai[(bb << 6) + r];
            xre = fmaf(ax, wr, fmaf(-ay, wi, xre));   // Re{A * w}
            xim = fmaf(ax, wi, fmaf(ay, wr, xim));    // Im{A * w}
            float t = fmaf(wr, c, wi * s);
            wi = fmaf(wi, c, -(wr * s));
            wr = t;
        }
        const float power = fmaf(xre, xre, xim * xim);
        const float lp = logf(power + 1e-10f);
        const float lk = logf((float)k * (1.0f / 4096.0f) + 1e-10f);
        s_lk = lk; s_lp = lp; s_lk2 = lk * lk; s_lklp = lk * lp;
    }

    for (int off = 32; off > 0; off >>= 1) {
        s_lk   += __shfl_down(s_lk, off, 64);
        s_lp   += __shfl_down(s_lp, off, 64);
        s_lk2  += __shfl_down(s_lk2, off, 64);
        s_lklp += __shfl_down(s_lklp, off, 64);
    }
    const int wid = tid >> 6, lane = tid & 63;
    if (lane == 0) red[wid] = make_float4(s_lk, s_lp, s_lk2, s_lklp);
    __syncthreads();
    if (tid == 0) {
        float4 t = red[0];
        t.x += red[1].x + red[2].x + red[3].x;
        t.y += red[1].y + red[2].y + red[3].y;
        t.z += red[1].z + red[2].z + red[3].z;
        t.w += red[1].w + red[2].w + red[3].w;
        partials[b * 8 + slice] = t;
    }
}

// ---------------------------------------------------------------------------
// logits[b, v] = 10*|amp*(cos(ph)*psi0 + sin(ph)*psi1)| / (|amp| + 1e-8)
// Finalize of the spectral regression (8 partials -> alpha) fused into
// thread 0 of each block. Hardware trig in revolution space; v=0 amp
// special-cased to sin(float(2pi)) to preserve the reference's residual
// against the 1e-8 norm floor.
// ---------------------------------------------------------------------------
__global__ __launch_bounds__(256) void logits_kernel(const float* __restrict__ psi,
                                                     const float4* __restrict__ partials,
                                                     float* __restrict__ out) {
    const int b = blockIdx.y;
    __shared__ float sh_alpha;
    if (threadIdx.x == 0) {
        float t0 = 0.f, t1 = 0.f, t2 = 0.f, t3 = 0.f;
#pragma unroll
        for (int i = 0; i < 8; ++i) {
            float4 p = partials[b * 8 + i];
            t0 += p.x; t1 += p.y; t2 += p.z; t3 += p.w;
        }
        const float mlk = t0 * (1.0f / NK_F);
        const float mlp = t1 * (1.0f / NK_F);
        const float cov = t3 - NK_F * mlk * mlp;
        const float var = t2 - NK_F * mlk * mlk;
        const float beta = -cov / (var + 1e-10f);
        float D = fminf(fmaxf((3.0f - beta) * 0.5f, 0.5f), 1.5f);
        sh_alpha = fminf(fmaxf(1.0f + 0.8f * (D - 1.0f), 0.1f), 3.0f);
    }
    __syncthreads();

    const float al = sh_alpha;
    const float p0 = psi[b * 4 + 0];
    const float p1 = psi[b * 4 + 1];
    const float alrev = al * INV2PI;
    const int j = blockIdx.x * 256 + threadIdx.x;   // [0, 32000) float4 index

    float tmp[4];
#pragma unroll
    for (int u = 0; u < 4; ++u) {
        const int v = j * 4 + u;
        const float lam = (float)v * (1.0f / 128000.0f);

        // amp = sin(2pi + al*lam) computed as sin over the exact f32-2pi residual
        float amp = __builtin_amdgcn_sinf(fmaf(alrev, lam, DREV));
        if (v == 0) amp = AMP0;

        // phase/2pi mod 1: 1 - 2*lam + C2*lam^2  ->  fract(C2*lam^2 - 2*lam)
        float y = lam * fmaf(C2, lam, -2.0f);
        y = y - floorf(y);
        float s, c;
        sincos_rev(y, s, c);

        const float coup = amp * fmaf(c, p0, s * p1) / (fabsf(amp) + 1e-8f);
        tmp[u] = 10.0f * fabsf(coup);
    }
    float4 res;
    res.x = tmp[0]; res.y = tmp[1]; res.z = tmp[2]; res.w = tmp[3];
    reinterpret_cast<float4*>(out)[(size_t)b * 32000 + j] = res;
}

// ---------------------------------------------------------------------------
// Fallback path (ws too small): round-1 single-kernel alpha + libm logits.
// ---------------------------------------------------------------------------
__global__ __launch_bounds__(256) void alpha_kernel(const float* __restrict__ x,
                                                    float* __restrict__ alpha_out) {
    const int b = blockIdx.x;
    const int tid = threadIdx.x;

    __shared__ float xs[T_LEN];
    __shared__ float2 Asm[64 * 64];
    __shared__ float rbuf[8];

    const float* xr = x + (size_t)b * T_LEN;
    for (int i = tid; i < T_LEN; i += 256) xs[i] = xr[i];
    __syncthreads();

    for (int i = 0; i < 16; ++i) {
        int p = tid + 256 * i;
        int b2 = p >> 6;
        int r  = p & 63;
        float re = 0.f, im = 0.f;
        int m = 0;
        for (int a = 0; a < 64; ++a) {
            float s, c;
            sincos_rev((float)m * (1.0f / 64.0f), s, c);
            float xv = xs[(a << 6) + b2];
            re = fmaf(xv, c, re);
            im = fmaf(xv, -s, im);
            m = (m + r) & 63;
        }
        Asm[(b2 << 6) + r] = make_float2(re, im);
    }
    __syncthreads();

    float lk_arr[8], lp_arr[8];
    float sum_lk = 0.f, sum_lp = 0.f;
#pragma unroll
    for (int i = 0; i < 8; ++i) {
        int k = KMIN + tid + 256 * i;
        lk_arr[i] = 0.f; lp_arr[i] = 0.f;
        if (k <= KMAX) {
            int r = k & 63;
            float xre = 0.f, xim = 0.f;
            int m = 0;
            for (int bb = 0; bb < 64; ++bb) {
                float s, c;
                sincos_rev((float)m * (1.0f / 4096.0f), s, c);
                float2 A = Asm[(bb << 6) + r];
                xre = fmaf(A.x, c, fmaf(A.y,  s, xre));
                xim = fmaf(A.y, c, fmaf(-A.x, s, xim));
                m = (m + k) & 4095;
            }
            float power = xre * xre + xim * xim;
            float lp = logf(power + 1e-10f);
            float lk = logf((float)k * (1.0f / 4096.0f) + 1e-10f);
            lk_arr[i] = lk; lp_arr[i] = lp;
            sum_lk += lk; sum_lp += lp;
        }
    }

    float a1 = sum_lk, a2 = sum_lp;
    for (int off = 32; off > 0; off >>= 1) {
        a1 += __shfl_down(a1, off, 64);
        a2 += __shfl_down(a2, off, 64);
    }
    const int wid = tid >> 6, lane = tid & 63;
    if (lane == 0) { rbuf[wid] = a1; rbuf[4 + wid] = a2; }
    __syncthreads();
    const float mean_lk = (rbuf[0] + rbuf[1] + rbuf[2] + rbuf[3]) * (1.0f / NK_F);
    const float mean_lp = (rbuf[4] + rbuf[5] + rbuf[6] + rbuf[7]) * (1.0f / NK_F);
    __syncthreads();

    float cov = 0.f, var = 0.f;
#pragma unroll
    for (int i = 0; i < 8; ++i) {
        int k = KMIN + tid + 256 * i;
        if (k <= KMAX) {
            float lkc = lk_arr[i] - mean_lk;
            float lpc = lp_arr[i] - mean_lp;
            cov = fmaf(lkc, lpc, cov);
            var = fmaf(lkc, lkc, var);
        }
    }
    float c1 = cov, c2 = var;
    for (int off = 32; off > 0; off >>= 1) {
        c1 += __shfl_down(c1, off, 64);
        c2 += __shfl_down(c2, off, 64);
    }
    if (lane == 0) { rbuf[wid] = c1; rbuf[4 + wid] = c2; }
    __syncthreads();
    if (tid == 0) {
        float covT = rbuf[0] + rbuf[1] + rbuf[2] + rbuf[3];
        float varT = rbuf[4] + rbuf[5] + rbuf[6] + rbuf[7];
        float beta = -covT / (varT + 1e-10f);
        float D = (3.0f - beta) * 0.5f;
        D = fminf(fmaxf(D, 0.5f), 1.5f);
        float al = 1.0f + 0.8f * (D - 1.0f);
        al = fminf(fmaxf(al, 0.1f), 3.0f);
        alpha_out[b] = al;
    }
}

__global__ __launch_bounds__(256) void logits_fallback_kernel(const float* __restrict__ psi,
                                                              const float* __restrict__ alpha,
                                                              float* __restrict__ out) {
    const int b = blockIdx.y;
    const int j = blockIdx.x * 256 + threadIdx.x;
    const float al = alpha[b];
    const float p0 = psi[b * 4 + 0];
    const float p1 = psi[b * 4 + 1];
    const float OMEGA = (float)(2.0 * M_PI);
    const float KWAVE = (float)(2.0 * M_PI / 0.5);

    float tmp[4];
#pragma unroll
    for (int u = 0; u < 4; ++u) {
        int v = j * 4 + u;
        float lam = (float)v / 128000.0f;
        float amp = sinf(OMEGA + al * lam);
        float ph  = OMEGA - KWAVE * lam + 0.01f * (lam * lam);
        float s = sinf(ph);
        float c = cosf(ph);
        float coup = (amp * c * p0 + amp * s * p1) / (fabsf(amp) + 1e-8f);
        tmp[u] = 10.0f * fabsf(coup);
    }
    float4 res;
    res.x = tmp[0]; res.y = tmp[1]; res.z = tmp[2]; res.w = tmp[3];
    reinterpret_cast<float4*>(out)[(size_t)b * 32000 + j] = res;
}

extern "C" void kernel_launch(void* const* d_in, const int* in_sizes, int n_in,
                              void* d_out, int out_size, void* d_ws, size_t ws_size,
                              hipStream_t stream) {
    const float* x   = (const float*)d_in[0];   // [32, 4096] f32
    const float* psi = (const float*)d_in[1];   // [32, 4] f32
    float* out = (float*)d_out;                 // [32, 128000] f32

    const size_t as_bytes = (size_t)32 * 4096 * sizeof(float2);     // 1 MiB
    const size_t part_bytes = (size_t)32 * 8 * sizeof(float4);      // 4 KiB

    if (ws_size >= as_bytes + part_bytes) {
        float2* As      = (float2*)d_ws;
        float4* partials = (float4*)((char*)d_ws + as_bytes);
        dft_stageA_kernel<<<256, 512, 0, stream>>>(x, As);
        spec_partial_kernel<<<dim3(8, 32), 256, 0, stream>>>(As, partials);
        logits_kernel<<<dim3(125, 32), 256, 0, stream>>>(psi, partials, out);
    } else {
        float* alpha = (float*)d_ws;            // 32 floats scratch
        alpha_kernel<<<32, 256, 0, stream>>>(x, alpha);
        logits_fallback_kernel<<<dim3(125, 32), 256, 0, stream>>>(psi, alpha, out);
    }
}

// Round 4
// 18.827 us; speedup vs baseline: 6.2876x; 1.1917x over previous
//
#include <hip/hip_runtime.h>
#include <math.h>

#ifndef M_PI
#define M_PI 3.14159265358979323846
#endif

constexpr int T_LEN = 4096;
constexpr int KMIN = 41;
constexpr int KMAX = 2047;
constexpr float NK_F = 2007.0f;
constexpr float INV2PI = 0.15915494309189535f;
constexpr float C2 = 0.0015915494f;      // 0.01 / (2*pi)
constexpr float DREV = 2.782754e-8f;     // (float(2pi) - 2pi) / (2pi)
constexpr float AMP0 = 1.7484556e-7f;    // sin(float(2pi)) == reference amp at v=0

__device__ __forceinline__ void sincos_rev(float rev, float& s, float& c) {
    // hardware v_sin/v_cos take REVOLUTIONS
    s = __builtin_amdgcn_sinf(rev);
    c = __builtin_amdgcn_cosf(rev);
}

// ---------------------------------------------------------------------------
// Fused alpha stage: 4096 = 16 x 256 DFT factorization.
//   Phase A (redundant per block, cheap): A[b2][r16] = sum_{a<16} x[256a+b2] W16^{r16*a}
//   Phase B: X[k] = sum_{b2<256} A[b2][k&15] * e^{-2pi i k b2/4096}, 2 thr/k.
// Then per-block partial regression sums (S_lk, S_lP, S_lk2, S_lklP).
// grid: (8 slices, 32 b) x 512 threads = 256 blocks (1/CU, 8 waves).
// ---------------------------------------------------------------------------
__global__ __launch_bounds__(512) void fused_alpha_kernel(const float* __restrict__ x,
                                                          float4* __restrict__ partials) {
    const int slice = blockIdx.x;
    const int b = blockIdx.y;
    const int tid = threadIdx.x;

    __shared__ __align__(16) float xs[T_LEN];      // reused as pb[] in phase B
    __shared__ float2 Ash[4096];                   // [b2][r16]
    __shared__ float4 red[8];

    const float* xr = x + (size_t)b * T_LEN;
    for (int i = tid; i < T_LEN; i += 512) xs[i] = xr[i];
    __syncthreads();

    // ---- Phase A: 8 outputs/thread, fixed r16 = tid & 15 ----
    {
        const int r16 = tid & 15;
        float s, c;
        sincos_rev((float)r16 * (1.0f / 16.0f), s, c);   // step = (c, -s)
#pragma unroll
        for (int i = 0; i < 8; ++i) {
            const int p = tid + 512 * i;                 // output index
            const int b2 = p >> 4;
            float wr = 1.f, wi = 0.f, re = 0.f, im = 0.f;
#pragma unroll
            for (int a = 0; a < 16; ++a) {
                const float xv = xs[(a << 8) + b2];
                re = fmaf(xv, wr, re);
                im = fmaf(xv, wi, im);
                const float t = fmaf(wr, c, wi * s);     // (wr,wi) *= (c,-s)
                wi = fmaf(wi, c, -(wr * s));
                wr = t;
            }
            Ash[(b2 << 4) + r16] = make_float2(re, im);  // word addr = 2p: conflict-free
        }
    }
    __syncthreads();

    // ---- Phase B: thread (t, half) handles k = KMIN + slice*256 + t,
    //      b2 in [half*128, half*128+128) ----
    const int t = tid & 255;
    const int half = tid >> 8;
    const int k = KMIN + (slice << 8) + t;
    float2* pb = (float2*)xs;                            // reuse xs storage

    float xre = 0.f, xim = 0.f;
    if (k <= KMAX) {
        const int r16 = k & 15;
        float s, c;
        sincos_rev((float)k * (1.0f / 4096.0f), s, c);   // step = (c, -s)
        // initial twiddle: e^{-2pi i k*(128*half)/4096} = e^{-2pi i (k*half)/32}
        float wr, wi;
        {
            float s0, c0;
            sincos_rev((float)((k * half) & 31) * (1.0f / 32.0f), s0, c0);
            wr = c0; wi = -s0;
        }
        const float2* Arow = Ash + (half << 11);         // b2 offset = half*128 -> *16
#pragma unroll 8
        for (int j = 0; j < 128; ++j) {
            const float2 A = Arow[(j << 4) + r16];
            xre = fmaf(A.x, wr, fmaf(-A.y, wi, xre));    // Re{A * w}
            xim = fmaf(A.x, wi, fmaf(A.y, wr, xim));     // Im{A * w}
            const float tt = fmaf(wr, c, wi * s);
            wi = fmaf(wi, c, -(wr * s));
            wr = tt;
        }
    }
    pb[tid] = make_float2(xre, xim);
    __syncthreads();

    // combine halves + regression terms (threads t < 256 active)
    float s_lk = 0.f, s_lp = 0.f, s_lk2 = 0.f, s_lklp = 0.f;
    if (half == 0 && k <= KMAX) {
        const float2 p0 = pb[tid];
        const float2 p1 = pb[tid + 256];
        const float re = p0.x + p1.x;
        const float im = p0.y + p1.y;
        const float power = fmaf(re, re, im * im);
        const float lp = logf(power + 1e-10f);
        const float lk = logf((float)k * (1.0f / 4096.0f) + 1e-10f);
        s_lk = lk; s_lp = lp; s_lk2 = lk * lk; s_lklp = lk * lp;
    }

    for (int off = 32; off > 0; off >>= 1) {
        s_lk   += __shfl_down(s_lk, off, 64);
        s_lp   += __shfl_down(s_lp, off, 64);
        s_lk2  += __shfl_down(s_lk2, off, 64);
        s_lklp += __shfl_down(s_lklp, off, 64);
    }
    const int wid = tid >> 6, lane = tid & 63;
    if (lane == 0) red[wid] = make_float4(s_lk, s_lp, s_lk2, s_lklp);
    __syncthreads();
    if (tid == 0) {
        float4 a = red[0];
#pragma unroll
        for (int w = 1; w < 8; ++w) {
            a.x += red[w].x; a.y += red[w].y;
            a.z += red[w].z; a.w += red[w].w;
        }
        partials[b * 8 + slice] = a;
    }
}

// ---------------------------------------------------------------------------
// logits[b, v] = 10*|amp*(cos(ph)*psi0 + sin(ph)*psi1)| / (|amp| + 1e-8)
// Spectral-regression finalize (8 partials -> alpha) fused into thread 0.
// Hardware trig in revolution space; v=0 amp special-cased to sin(float(2pi)).
// ---------------------------------------------------------------------------
__global__ __launch_bounds__(256) void logits_kernel(const float* __restrict__ psi,
                                                     const float4* __restrict__ partials,
                                                     float* __restrict__ out) {
    const int b = blockIdx.y;
    __shared__ float sh_alpha;
    if (threadIdx.x == 0) {
        float t0 = 0.f, t1 = 0.f, t2 = 0.f, t3 = 0.f;
#pragma unroll
        for (int i = 0; i < 8; ++i) {
            float4 p = partials[b * 8 + i];
            t0 += p.x; t1 += p.y; t2 += p.z; t3 += p.w;
        }
        const float mlk = t0 * (1.0f / NK_F);
        const float mlp = t1 * (1.0f / NK_F);
        const float cov = t3 - NK_F * mlk * mlp;
        const float var = t2 - NK_F * mlk * mlk;
        const float beta = -cov / (var + 1e-10f);
        float D = fminf(fmaxf((3.0f - beta) * 0.5f, 0.5f), 1.5f);
        sh_alpha = fminf(fmaxf(1.0f + 0.8f * (D - 1.0f), 0.1f), 3.0f);
    }
    __syncthreads();

    const float al = sh_alpha;
    const float p0 = psi[b * 4 + 0];
    const float p1 = psi[b * 4 + 1];
    const float alrev = al * INV2PI;
    const int j = blockIdx.x * 256 + threadIdx.x;   // [0, 32000) float4 index

    float tmp[4];
#pragma unroll
    for (int u = 0; u < 4; ++u) {
        const int v = j * 4 + u;
        const float lam = (float)v * (1.0f / 128000.0f);

        // amp = sin(2pi + al*lam), computed over the exact f32-2pi residual
        float amp = __builtin_amdgcn_sinf(fmaf(alrev, lam, DREV));
        if (v == 0) amp = AMP0;

        // phase/2pi mod 1: fract(C2*lam^2 - 2*lam)
        float y = lam * fmaf(C2, lam, -2.0f);
        y = y - floorf(y);
        float s, c;
        sincos_rev(y, s, c);

        const float coup = amp * fmaf(c, p0, s * p1) / (fabsf(amp) + 1e-8f);
        tmp[u] = 10.0f * fabsf(coup);
    }
    float4 res;
    res.x = tmp[0]; res.y = tmp[1]; res.z = tmp[2]; res.w = tmp[3];
    reinterpret_cast<float4*>(out)[(size_t)b * 32000 + j] = res;
}

extern "C" void kernel_launch(void* const* d_in, const int* in_sizes, int n_in,
                              void* d_out, int out_size, void* d_ws, size_t ws_size,
                              hipStream_t stream) {
    const float* x   = (const float*)d_in[0];   // [32, 4096] f32
    const float* psi = (const float*)d_in[1];   // [32, 4] f32
    float* out = (float*)d_out;                 // [32, 128000] f32

    float4* partials = (float4*)d_ws;           // 32*8 float4 = 4 KiB

    fused_alpha_kernel<<<dim3(8, 32), 512, 0, stream>>>(x, partials);
    logits_kernel<<<dim3(125, 32), 256, 0, stream>>>(psi, partials, out);
}